// Round 4
// baseline (145.105 us; speedup 1.0000x reference)
//
#include <hip/hip_runtime.h>
#include <hip/hip_bf16.h>

#define B_SZ 2048
#define H_SZ 200
#define EMB 128
#define HID 256
#define KW 160          // padded K in W1TB (130 real + zero pad)

typedef short bf16x8 __attribute__((ext_vector_type(8)));
typedef float f32x4 __attribute__((ext_vector_type(4)));

#define WAIT_VM(n) asm volatile("s_waitcnt vmcnt(" #n ")" ::: "memory")
#define WAIT_LGKM  asm volatile("s_waitcnt lgkmcnt(0)" ::: "memory")
#define BAR        asm volatile("s_barrier" ::: "memory")

__device__ __forceinline__ unsigned short bfc(float x) {
    unsigned u = __float_as_uint(x);
    u += 0x7FFFu + ((u >> 16) & 1u);
    return (unsigned short)(u >> 16);
}
__device__ __forceinline__ float bf2f(unsigned short h) {
    return __uint_as_float(((unsigned)h) << 16);
}

// W1 [130][256] fp32 -> W1TB [256][160] bf16 (k<130 real, 130..159 zero)
__global__ void prep_w1t(const float* __restrict__ W1, unsigned short* __restrict__ W1TB) {
    int i = blockIdx.x * 256 + threadIdx.x;      // 256*160
    int n = i / KW;
    int k = i - n * KW;
    float v = (k < 130) ? W1[k * HID + n] : 0.f;
    W1TB[i] = bfc(v);
}

// embed_history fp32 -> bf16 table
__global__ void prep_ehb(const float* __restrict__ eh, unsigned short* __restrict__ ehb) {
    size_t t = (size_t)blockIdx.x * 256 + threadIdx.x;
    const float4* src = (const float4*)eh + t * 2;
    float4 a = src[0], b = src[1];
    uint4 o;
    o.x = (unsigned)bfc(a.x) | ((unsigned)bfc(a.y) << 16);
    o.y = (unsigned)bfc(a.z) | ((unsigned)bfc(a.w) << 16);
    o.z = (unsigned)bfc(b.x) | ((unsigned)bfc(b.y) << 16);
    o.w = (unsigned)bfc(b.z) | ((unsigned)bfc(b.w) << 16);
    ((uint4*)ehb)[t] = o;
}

__device__ __forceinline__ void gld_lds16(const unsigned short* g, unsigned short* l) {
    __builtin_amdgcn_global_load_lds(
        (const __attribute__((address_space(1))) void*)(g),
        (__attribute__((address_space(3))) void*)(l),
        16, 0, 0);
}

// One block per b. Swapped-operand MFMA: D = Bb^T @ A^T = hidden^T, so the
// relu*W2 contraction over n is lane-local (8 fma) + 2 shuffles. Dist cols
// folded into K (ks=4). u computed per-tile by all waves.
__global__ __launch_bounds__(512, 4) void attn_kernel(
    const int* __restrict__ history, const int* __restrict__ target,
    const float* __restrict__ td, const unsigned short* __restrict__ ehb,
    const float* __restrict__ et, const unsigned short* __restrict__ W1TB,
    const float* __restrict__ b1, const float* __restrict__ W2,
    const float* __restrict__ Wd, const float* __restrict__ bd,
    float* __restrict__ out)
{
    __shared__ __align__(16) unsigned short Abuf[4][64][128];  // 64 KB, chunk-swizzled
    __shared__ float red[4][64][9];
    __shared__ unsigned Adist[256];        // packed bf16 (d0,d1) per row
    __shared__ int idxs[256];
    __shared__ float t_f32[EMB];
    __shared__ __align__(16) unsigned short tbf[EMB];
    __shared__ float u_arr[256];
    __shared__ float finred[8];

    const int tid = threadIdx.x;
    const int b   = blockIdx.x;
    const int tgt = target[b];

    // ---- phase 0: stage t row (f32 + bf16), dist sigmoid, history idx ----
    if (tid < 128) {
        float tf = et[(size_t)tgt * EMB + tid];
        t_f32[tid] = tf;
        tbf[tid] = bfc(tf);
    } else if (tid < 384) {
        const int m0 = tid - 128;
        if (m0 < H_SZ) {
            const int row = b * H_SZ + m0;
            idxs[m0] = history[row];
            float x0 = td[(size_t)row * 2 + 0] * 1000.f;
            float x1 = td[(size_t)row * 2 + 1] * 1000.f;
            float d0 = x0 * Wd[0] + x1 * Wd[2] + bd[0];
            float d1 = x0 * Wd[1] + x1 * Wd[3] + bd[1];
            d0 = 1.f / (1.f + expf(-d0));
            d1 = 1.f / (1.f + expf(-d1));
            Adist[m0] = (unsigned)bfc(d0) | ((unsigned)bfc(d1) << 16);
        } else {
            Adist[m0] = 0u;                // rows 200..255: zero (read by ks=4 frag)
        }
    }
    WAIT_LGKM; BAR;

    const int l  = tid & 63;
    const int w  = tid >> 6;
    const int lr = l & 15;
    const int lq = l >> 4;

    // ---- issue ALL gather DMAs first (latency hides under B_b build) ----
    // LDS[r][c] = H[r][c ^ (r&7)] (16B chunks), linear dest per rule 21
#pragma unroll
    for (int t = 0; t < 3; ++t) {
#pragma unroll
        for (int j = 0; j < 2; ++j) {
            const int rd = w * 8 + j * 4 + lq;
            const int cc = lr ^ (rd & 7);
            gld_lds16(ehb + (size_t)idxs[t * 64 + rd] * EMB + cc * 8,
                      &Abuf[t][w * 8 + j * 4][0]);
        }
    }
#pragma unroll
    for (int j = 0; j < 2; ++j) {          // tile 3: 8 rows, all waves duplicate
        const int rd = j * 4 + lq;
        const int cc = lr ^ (rd & 7);
        gld_lds16(ehb + (size_t)idxs[192 + rd] * EMB + cc * 8, &Abuf[3][j * 4][0]);
    }

    // ---- B_b = t-scaled W1 strips as MFMA *A*-operand frags (n = lane&15) ----
    bf16x8 bfrA[2][5];
    f32x4 b1v[2], w2v[2];
#pragma unroll
    for (int nt = 0; nt < 2; ++nt) {
        const int n = w * 32 + nt * 16 + lr;
        b1v[nt] = *reinterpret_cast<const f32x4*>(b1 + w * 32 + nt * 16 + lq * 4);
        w2v[nt] = *reinterpret_cast<const f32x4*>(W2 + w * 32 + nt * 16 + lq * 4);
#pragma unroll
        for (int ks = 0; ks < 4; ++ks) {
            bf16x8 wv = *reinterpret_cast<const bf16x8*>(W1TB + n * KW + ks * 32 + lq * 8);
            bf16x8 o;
#pragma unroll
            for (int j = 0; j < 8; ++j)
                o[j] = (short)bfc(bf2f((unsigned short)wv[j]) * t_f32[ks * 32 + lq * 8 + j]);
            bfrA[nt][ks] = o;
        }
        bfrA[nt][4] = *reinterpret_cast<const bf16x8*>(W1TB + n * KW + 128 + lq * 8);
    }

    // t as bf16 regs for the per-tile u-compute
    const int uo = tid & 7, um = tid >> 3;
    const bf16x8 tbu0 = *reinterpret_cast<const bf16x8*>(tbf + (2 * uo) * 8);
    const bf16x8 tbu1 = *reinterpret_cast<const bf16x8*>(tbf + (2 * uo + 1) * 8);

    // ---- main loop: counted vmcnt, one barrier per tile ----
#pragma unroll
    for (int t = 0; t < 4; ++t) {
        if (t == 0)      WAIT_VM(6);
        else if (t == 1) WAIT_VM(4);
        else if (t == 2) WAIT_VM(2);
        else             WAIT_VM(0);
        BAR;

        const int mc = (t == 3) ? 1 : 4;

        f32x4 acc[4][2];
#pragma unroll
        for (int mt = 0; mt < 4; ++mt)
#pragma unroll
            for (int nt = 0; nt < 2; ++nt)
                acc[mt][nt] = (f32x4){0.f, 0.f, 0.f, 0.f};

#pragma unroll
        for (int ks = 0; ks < 5; ++ks) {
#pragma unroll
            for (int mt = 0; mt < 4; ++mt) if (mt < mc) {
                const int ar = mt * 16 + lr;
                bf16x8 af;
                if (ks < 4) {
                    af = *reinterpret_cast<const bf16x8*>(
                        &Abuf[t][ar][(((ks * 4 + lq) ^ (ar & 7)) * 8)]);
                } else {
                    uint4 tv4 = make_uint4((lq == 0) ? Adist[t * 64 + ar] : 0u, 0u, 0u, 0u);
                    af = *reinterpret_cast<bf16x8*>(&tv4);
                }
#pragma unroll
                for (int nt = 0; nt < 2; ++nt)
                    acc[mt][nt] = __builtin_amdgcn_mfma_f32_16x16x32_bf16(
                        bfrA[nt][ks], af, acc[mt][nt], 0, 0, 0);
            }
        }

        // ---- u = h.t for this tile's rows (all waves, 8 thr/row) ----
        {
            const unsigned short* Ar = &Abuf[t][um][0];
            bf16x8 h0 = *reinterpret_cast<const bf16x8*>(Ar + (((2 * uo)     ^ (um & 7)) * 8));
            bf16x8 h1 = *reinterpret_cast<const bf16x8*>(Ar + (((2 * uo + 1) ^ (um & 7)) * 8));
            float ua = 0.f;
#pragma unroll
            for (int j = 0; j < 8; ++j) {
                ua += bf2f((unsigned short)h0[j]) * bf2f((unsigned short)tbu0[j]);
                ua += bf2f((unsigned short)h1[j]) * bf2f((unsigned short)tbu1[j]);
            }
            ua += __shfl_xor(ua, 1);
            ua += __shfl_xor(ua, 2);
            ua += __shfl_xor(ua, 4);
            if (uo == 0) u_arr[t * 64 + um] = ua;
        }

        // ---- epilogue: lane-local relu*W2 over 8 n's, then 2 shuffles ----
#pragma unroll
        for (int mt = 0; mt < 4; ++mt) if (mt < mc) {
            float s = 0.f;
#pragma unroll
            for (int nt = 0; nt < 2; ++nt)
#pragma unroll
                for (int r = 0; r < 4; ++r)
                    s += fmaxf(acc[mt][nt][r] + b1v[nt][r], 0.f) * w2v[nt][r];
            s += __shfl_xor(s, 16);
            s += __shfl_xor(s, 32);
            if (l < 16) red[t][mt * 16 + l][w] = s;
        }
    }

    WAIT_LGKM; BAR;

    // ---- final: attn -> exp/mask, pooled sigmoid ----
    if (tid < 256) {
        const int tt = tid >> 6, mr = tid & 63;
        float attn = 0.f;
#pragma unroll
        for (int ww = 0; ww < 8; ++ww) attn += red[tt][mr][ww];
        const bool valid = (tid < H_SZ) && (idxs[tid] != tgt);
        float e  = valid ? expf(attn) : 0.f;
        float se = e;
        float su = valid ? e * u_arr[tid] : 0.f;
#pragma unroll
        for (int off = 1; off < 64; off <<= 1) {
            se += __shfl_xor(se, off);
            su += __shfl_xor(su, off);
        }
        if (l == 0) { finred[w * 2] = se; finred[w * 2 + 1] = su; }
    }
    WAIT_LGKM; BAR;
    if (tid == 0) {
        float SE = 0.f, SU = 0.f;
#pragma unroll
        for (int ww = 0; ww < 4; ++ww) { SE += finred[2 * ww]; SU += finred[2 * ww + 1]; }
        out[b] = 1.f / (1.f + expf(-SU / sqrtf(SE)));
    }
}

extern "C" void kernel_launch(void* const* d_in, const int* in_sizes, int n_in,
                              void* d_out, int out_size, void* d_ws, size_t ws_size,
                              hipStream_t stream) {
    const int*   history = (const int*)d_in[0];
    const int*   target  = (const int*)d_in[1];
    const float* td      = (const float*)d_in[4];
    const float* eh      = (const float*)d_in[5];
    const float* et      = (const float*)d_in[6];
    const float* W1      = (const float*)d_in[7];
    const float* b1      = (const float*)d_in[8];
    const float* W2      = (const float*)d_in[9];
    const float* Wd      = (const float*)d_in[10];
    const float* bd      = (const float*)d_in[11];
    float* out = (float*)d_out;

    char* ws = (char*)d_ws;
    unsigned short* W1TB = (unsigned short*)ws;            // 256*160*2 = 81,920 B
    unsigned short* ehb  = (unsigned short*)(ws + 81920);  // 25,600,000 B

    prep_w1t<<<HID * KW / 256, 256, 0, stream>>>(W1, W1TB);
    prep_ehb<<<1600000 / 256, 256, 0, stream>>>(eh, ehb);
    attn_kernel<<<B_SZ, 512, 0, stream>>>(history, target, td, ehb, et, W1TB,
                                          b1, W2, Wd, bd, out);
}

// Round 5
// 120.746 us; speedup vs baseline: 1.2017x; 1.2017x over previous
//
#include <hip/hip_runtime.h>
#include <hip/hip_bf16.h>

#define B_SZ 2048
#define H_SZ 200
#define EMB 128
#define HID 256
#define KW 160          // padded K in W1TB (130 real + zero pad)

typedef short bf16x8 __attribute__((ext_vector_type(8)));
typedef float f32x4 __attribute__((ext_vector_type(4)));

#define WAIT_VM(n) asm volatile("s_waitcnt vmcnt(" #n ")" ::: "memory")
#define WAIT_LGKM  asm volatile("s_waitcnt lgkmcnt(0)" ::: "memory")
#define BAR        asm volatile("s_barrier" ::: "memory")

__device__ __forceinline__ unsigned short bfc(float x) {
    unsigned u = __float_as_uint(x);
    u += 0x7FFFu + ((u >> 16) & 1u);
    return (unsigned short)(u >> 16);
}
__device__ __forceinline__ float bf2f(unsigned short h) {
    return __uint_as_float(((unsigned)h) << 16);
}

// W1 [130][256] fp32 -> W1TB [256][160] bf16 (k<130 real, 130..159 zero)
__global__ void prep_w1t(const float* __restrict__ W1, unsigned short* __restrict__ W1TB) {
    int i = blockIdx.x * 256 + threadIdx.x;      // 256*160
    int n = i / KW;
    int k = i - n * KW;
    float v = (k < 130) ? W1[k * HID + n] : 0.f;
    W1TB[i] = bfc(v);
}

// embed_history fp32 -> bf16 table
__global__ void prep_ehb(const float* __restrict__ eh, unsigned short* __restrict__ ehb) {
    size_t t = (size_t)blockIdx.x * 256 + threadIdx.x;
    const float4* src = (const float4*)eh + t * 2;
    float4 a = src[0], b = src[1];
    uint4 o;
    o.x = (unsigned)bfc(a.x) | ((unsigned)bfc(a.y) << 16);
    o.y = (unsigned)bfc(a.z) | ((unsigned)bfc(a.w) << 16);
    o.z = (unsigned)bfc(b.x) | ((unsigned)bfc(b.y) << 16);
    o.w = (unsigned)bfc(b.z) | ((unsigned)bfc(b.w) << 16);
    ((uint4*)ehb)[t] = o;
}

__device__ __forceinline__ void gld_lds16(const unsigned short* g, unsigned short* l) {
    __builtin_amdgcn_global_load_lds(
        (const __attribute__((address_space(1))) void*)(g),
        (__attribute__((address_space(3))) void*)(l),
        16, 0, 0);
}

// One block per b. R3 ordering (bfrA build -> vmcnt(0) -> issue all DMAs ->
// counted-vmcnt loop) + R4 swapped-operand epilogue (lane-local relu*W2).
// Tile-3 gathers deduped to waves 0/1 with per-wave vmcnt literals.
__global__ __launch_bounds__(512, 4) void attn_kernel(
    const int* __restrict__ history, const int* __restrict__ target,
    const float* __restrict__ td, const unsigned short* __restrict__ ehb,
    const float* __restrict__ et, const unsigned short* __restrict__ W1TB,
    const float* __restrict__ b1, const float* __restrict__ W2,
    const float* __restrict__ Wd, const float* __restrict__ bd,
    float* __restrict__ out)
{
    __shared__ __align__(16) unsigned short Abuf[4][64][128];  // 64 KB, chunk-swizzled
    __shared__ float red[4][64][9];
    __shared__ unsigned Adist[256];        // packed bf16 (d0,d1) per row
    __shared__ int idxs[256];
    __shared__ float t_f32[EMB];
    __shared__ __align__(16) unsigned short tbf[EMB];
    __shared__ float u_arr[256];
    __shared__ float finred[8];

    const int tid = threadIdx.x;
    const int b   = blockIdx.x;
    const int tgt = target[b];

    // ---- phase 0: stage t row (f32 + bf16), dist sigmoid, history idx ----
    if (tid < 128) {
        float tf = et[(size_t)tgt * EMB + tid];
        t_f32[tid] = tf;
        tbf[tid] = bfc(tf);
    } else if (tid < 384) {
        const int m0 = tid - 128;
        if (m0 < H_SZ) {
            const int row = b * H_SZ + m0;
            idxs[m0] = history[row];
            float x0 = td[(size_t)row * 2 + 0] * 1000.f;
            float x1 = td[(size_t)row * 2 + 1] * 1000.f;
            float d0 = x0 * Wd[0] + x1 * Wd[2] + bd[0];
            float d1 = x0 * Wd[1] + x1 * Wd[3] + bd[1];
            d0 = 1.f / (1.f + expf(-d0));
            d1 = 1.f / (1.f + expf(-d1));
            Adist[m0] = (unsigned)bfc(d0) | ((unsigned)bfc(d1) << 16);
        } else {
            Adist[m0] = 0u;                // rows 200..255: zero
        }
    }
    WAIT_LGKM; BAR;

    const int l  = tid & 63;
    const int w  = tid >> 6;
    const int lr = l & 15;
    const int lq = l >> 4;

    // ---- B_b = t-scaled W1 strips as MFMA *A*-operand frags (n = lane&15) ----
    bf16x8 bfrA[2][5];
    f32x4 b1v[2], w2v[2];
#pragma unroll
    for (int nt = 0; nt < 2; ++nt) {
        const int n = w * 32 + nt * 16 + lr;
        b1v[nt] = *reinterpret_cast<const f32x4*>(b1 + w * 32 + nt * 16 + lq * 4);
        w2v[nt] = *reinterpret_cast<const f32x4*>(W2 + w * 32 + nt * 16 + lq * 4);
#pragma unroll
        for (int ks = 0; ks < 4; ++ks) {
            bf16x8 wv = *reinterpret_cast<const bf16x8*>(W1TB + n * KW + ks * 32 + lq * 8);
            bf16x8 o;
#pragma unroll
            for (int j = 0; j < 8; ++j)
                o[j] = (short)bfc(bf2f((unsigned short)wv[j]) * t_f32[ks * 32 + lq * 8 + j]);
            bfrA[nt][ks] = o;
        }
        bfrA[nt][4] = *reinterpret_cast<const bf16x8*>(W1TB + n * KW + 128 + lq * 8);
    }

    // t as bf16 regs for the per-tile u-compute
    const int uo = tid & 7, um = tid >> 3;
    const bf16x8 tbu0 = *reinterpret_cast<const bf16x8*>(tbf + (2 * uo) * 8);
    const bf16x8 tbu1 = *reinterpret_cast<const bf16x8*>(tbf + (2 * uo + 1) * 8);

    // drain all compiler vmem so hand-counted vmcnt below is exact (R3 ordering)
    WAIT_VM(0);

    // ---- issue ALL gather DMAs (quad buffer) ----
    // LDS[r][c] = H[r][c ^ (r&7)] (16B chunks), linear dest per rule 21
#pragma unroll
    for (int t = 0; t < 3; ++t) {
#pragma unroll
        for (int j = 0; j < 2; ++j) {
            const int rd = w * 8 + j * 4 + lq;
            const int cc = lr ^ (rd & 7);
            gld_lds16(ehb + (size_t)idxs[t * 64 + rd] * EMB + cc * 8,
                      &Abuf[t][w * 8 + j * 4][0]);
        }
    }
    // tile 3 (8 real rows): ONLY waves 0 and 1 issue (one instr = 4 rows each)
    if (w < 2) {
        const int rd = w * 4 + lq;
        const int cc = lr ^ (rd & 7);
        gld_lds16(ehb + (size_t)idxs[192 + rd] * EMB + cc * 8, &Abuf[3][w * 4][0]);
    }

    // ---- main loop: counted per-wave vmcnt, one barrier per tile ----
#pragma unroll
    for (int t = 0; t < 4; ++t) {
        // waves 0/1 have 7 DMAs outstanding, waves 2-7 have 6
        if (t == 0)      { if (w < 2) WAIT_VM(5); else WAIT_VM(4); }
        else if (t == 1) { if (w < 2) WAIT_VM(3); else WAIT_VM(2); }
        else if (t == 2) { if (w < 2) WAIT_VM(1); else WAIT_VM(0); }
        else             WAIT_VM(0);
        BAR;

        const int mc = (t == 3) ? 1 : 4;

        f32x4 acc[4][2];
#pragma unroll
        for (int mt = 0; mt < 4; ++mt)
#pragma unroll
            for (int nt = 0; nt < 2; ++nt)
                acc[mt][nt] = (f32x4){0.f, 0.f, 0.f, 0.f};

#pragma unroll
        for (int ks = 0; ks < 5; ++ks) {
#pragma unroll
            for (int mt = 0; mt < 4; ++mt) if (mt < mc) {
                const int ar = mt * 16 + lr;
                bf16x8 af;
                if (ks < 4) {
                    af = *reinterpret_cast<const bf16x8*>(
                        &Abuf[t][ar][(((ks * 4 + lq) ^ (ar & 7)) * 8)]);
                } else {
                    uint4 tv4 = make_uint4((lq == 0) ? Adist[t * 64 + ar] : 0u, 0u, 0u, 0u);
                    af = *reinterpret_cast<bf16x8*>(&tv4);
                }
#pragma unroll
                for (int nt = 0; nt < 2; ++nt)
                    acc[mt][nt] = __builtin_amdgcn_mfma_f32_16x16x32_bf16(
                        bfrA[nt][ks], af, acc[mt][nt], 0, 0, 0);
            }
        }

        // ---- u = h.t for this tile's rows (all waves, 8 thr/row) ----
        {
            const unsigned short* Ar = &Abuf[t][um][0];
            bf16x8 h0 = *reinterpret_cast<const bf16x8*>(Ar + (((2 * uo)     ^ (um & 7)) * 8));
            bf16x8 h1 = *reinterpret_cast<const bf16x8*>(Ar + (((2 * uo + 1) ^ (um & 7)) * 8));
            float ua = 0.f;
#pragma unroll
            for (int j = 0; j < 8; ++j) {
                ua += bf2f((unsigned short)h0[j]) * bf2f((unsigned short)tbu0[j]);
                ua += bf2f((unsigned short)h1[j]) * bf2f((unsigned short)tbu1[j]);
            }
            ua += __shfl_xor(ua, 1);
            ua += __shfl_xor(ua, 2);
            ua += __shfl_xor(ua, 4);
            if (uo == 0) u_arr[t * 64 + um] = ua;
        }

        // ---- epilogue: lane-local relu*W2 over 8 n's, then 2 shuffles ----
#pragma unroll
        for (int mt = 0; mt < 4; ++mt) if (mt < mc) {
            float s = 0.f;
#pragma unroll
            for (int nt = 0; nt < 2; ++nt)
#pragma unroll
                for (int r = 0; r < 4; ++r)
                    s += fmaxf(acc[mt][nt][r] + b1v[nt][r], 0.f) * w2v[nt][r];
            s += __shfl_xor(s, 16);
            s += __shfl_xor(s, 32);
            if (l < 16) red[t][mt * 16 + l][w] = s;
        }
    }

    WAIT_LGKM; BAR;

    // ---- final: attn -> exp/mask, pooled sigmoid ----
    if (tid < 256) {
        const int tt = tid >> 6, mr = tid & 63;
        float attn = 0.f;
#pragma unroll
        for (int ww = 0; ww < 8; ++ww) attn += red[tt][mr][ww];
        const bool valid = (tid < H_SZ) && (idxs[tid] != tgt);
        float e  = valid ? expf(attn) : 0.f;
        float se = e;
        float su = valid ? e * u_arr[tid] : 0.f;
#pragma unroll
        for (int off = 1; off < 64; off <<= 1) {
            se += __shfl_xor(se, off);
            su += __shfl_xor(su, off);
        }
        if (l == 0) { finred[w * 2] = se; finred[w * 2 + 1] = su; }
    }
    WAIT_LGKM; BAR;
    if (tid == 0) {
        float SE = 0.f, SU = 0.f;
#pragma unroll
        for (int ww = 0; ww < 4; ++ww) { SE += finred[2 * ww]; SU += finred[2 * ww + 1]; }
        out[b] = 1.f / (1.f + expf(-SU / sqrtf(SE)));
    }
}

extern "C" void kernel_launch(void* const* d_in, const int* in_sizes, int n_in,
                              void* d_out, int out_size, void* d_ws, size_t ws_size,
                              hipStream_t stream) {
    const int*   history = (const int*)d_in[0];
    const int*   target  = (const int*)d_in[1];
    const float* td      = (const float*)d_in[4];
    const float* eh      = (const float*)d_in[5];
    const float* et      = (const float*)d_in[6];
    const float* W1      = (const float*)d_in[7];
    const float* b1      = (const float*)d_in[8];
    const float* W2      = (const float*)d_in[9];
    const float* Wd      = (const float*)d_in[10];
    const float* bd      = (const float*)d_in[11];
    float* out = (float*)d_out;

    char* ws = (char*)d_ws;
    unsigned short* W1TB = (unsigned short*)ws;            // 256*160*2 = 81,920 B
    unsigned short* ehb  = (unsigned short*)(ws + 81920);  // 25,600,000 B

    prep_w1t<<<HID * KW / 256, 256, 0, stream>>>(W1, W1TB);
    prep_ehb<<<1600000 / 256, 256, 0, stream>>>(eh, ehb);
    attn_kernel<<<B_SZ, 512, 0, stream>>>(history, target, td, ehb, et, W1TB,
                                          b1, W2, Wd, bd, out);
}